// Round 6
// baseline (267.316 us; speedup 1.0000x reference)
//
#include <hip/hip_runtime.h>
#include <stdint.h>

// ---------------------------------------------------------------------------
// MaxSim InfoNCE on MI355X (gfx950)
//   image_tokens: [128, 196, 512] fp32   (d_in[0])
//   text_tokens : [128,  64, 512] fp32   (d_in[1])
//   out         : scalar fp32 loss
//
// R6: persistent INT8 GEMM. 512 blocks x 16 tasks (pr fixed per block,
// b2 = (j&7) + 8t so one XCD's blocks share an image tile). R2/R5's proven
// prefetch-before-compute dbuf K-loop, with the NEXT task's step-0 DMA
// issued before the current task's last compute -> no cold restarts.
// Tile-12 rebalance: 26/26 MFMA per wave (was 28/24). Loss fused via
// finish-counter in the last block.
// ---------------------------------------------------------------------------

typedef __attribute__((ext_vector_type(4))) int i4v;     // 16 i8 / 4 i32

#define BB 128
#define TT 64
#define II 196
#define IP 208          // padded image tokens per batch (13*16)
#define DD 512
#define BKK 64          // K bytes (=elems) per staging step
#define NTASK 16
#define LSTR 132

static __device__ __forceinline__ void async16(const void* g, void* l) {
  __builtin_amdgcn_global_load_lds(
      (const __attribute__((address_space(1))) void*)g,
      (__attribute__((address_space(3))) void*)l, 16, 0, 0);
}

static __device__ __forceinline__ unsigned q8(float x) {
  float r = rintf(x * 32.0f);                 // RNE, scale 32 (clip 3.97 sigma)
  r = fmaxf(-127.0f, fminf(127.0f, r));
  return (unsigned)((int)r) & 255u;
}
static __device__ __forceinline__ unsigned pk4(float a, float b, float c, float d) {
  return q8(a) | (q8(b) << 8) | (q8(c) << 16) | (q8(d) << 24);
}

// ---- pack: fp32 -> i8 (scale 32). text [128*64,512]; image padded
// ---- [128,208,512], pad rows zeroed. 16 elems / thread.
#define TEXT_BLOCKS 1024     // 1024*256*16 = 128*64*512
#define IMG_BLOCKS  3328     // 3328*256*16 = 128*208*512
__global__ void pack_k(const float* __restrict__ img, const float* __restrict__ txt,
                       uint4* __restrict__ imgq, uint4* __restrict__ txtq) {
  uint4 o;
  if (blockIdx.x < TEXT_BLOCKS) {
    int c = blockIdx.x * 256 + threadIdx.x;         // chunk of 16 elems
    const float4* in4 = (const float4*)txt;
    float4 f0 = in4[4 * c], f1 = in4[4 * c + 1], f2 = in4[4 * c + 2], f3 = in4[4 * c + 3];
    o.x = pk4(f0.x, f0.y, f0.z, f0.w);
    o.y = pk4(f1.x, f1.y, f1.z, f1.w);
    o.z = pk4(f2.x, f2.y, f2.z, f2.w);
    o.w = pk4(f3.x, f3.y, f3.z, f3.w);
    txtq[c] = o;
  } else {
    int c = (blockIdx.x - TEXT_BLOCKS) * 256 + threadIdx.x;
    int e = c * 16;
    int k = e & (DD - 1);
    int tok = e >> 9;
    int b2 = tok / IP;
    int r = tok - b2 * IP;
    if (r < II) {
      const float4* in4 = (const float4*)(img + ((size_t)(b2 * II + r) * DD + k));
      float4 f0 = in4[0], f1 = in4[1], f2 = in4[2], f3 = in4[3];
      o.x = pk4(f0.x, f0.y, f0.z, f0.w);
      o.y = pk4(f1.x, f1.y, f1.z, f1.w);
      o.z = pk4(f2.x, f2.y, f2.z, f2.w);
      o.w = pk4(f3.x, f3.y, f3.z, f3.w);
    } else {
      o = make_uint4(0u, 0u, 0u, 0u);
    }
    imgq[c] = o;
  }
}

// ---- persistent GEMM + fused max/mean + fused loss ----
// grid: 512 blocks, 256 threads (4 waves). Block j: pr = j>>3 (fixed),
// tasks t=0..15: b2 = (j&7) + 8t.
__global__ __launch_bounds__(256, 2) void maxsim_gemm_k(
    const char* __restrict__ A,    // text i8 [128*64, 512]
    const char* __restrict__ Bm,   // image i8 [128*208, 512]
    float* __restrict__ sim,       // [128,128] mean-of-max
    int* __restrict__ counter,     // zeroed each launch
    float* __restrict__ out)       // scalar loss
{
  // GEMM phase layout inside smem (44,032 B) / loss phase overlay (67,584 B)
  __shared__ __align__(16) char smem[BB * LSTR * 4];   // 67,584 B
  char* As0 = smem;                       //  8,192
  char* As1 = smem + 8192;                //  8,192
  char* Bs0 = smem + 16384;               // 13,312
  char* Bs1 = smem + 29696;               // 13,312
  int*  partial = (int*)(smem + 43008);   //  1,024  [2][128]
  __shared__ float red[4];
  __shared__ int lastflag;

  const int j   = blockIdx.x;
  const int pr  = j >> 3;           // text pair: b1 in {2pr, 2pr+1}
  const int b2_0 = j & 7;
  const int tid = threadIdx.x;
  const int w = tid >> 6, l = tid & 63;
  const int m = l & 15, q = l >> 4;
  const int waveM = w >> 1;
  const int waveN = w & 1;

  // chunk -> byte offset (i8: byte == elem), XOR chunk swizzle:
  // physical chunk p of row r holds logical chunk p ^ ((r>>1)&3)
  const int ca0 = tid, ca1 = tid + 256;
  const int cb0 = tid, cb1 = tid + 256, cb2 = tid + 512, cb3 = 768 + l;
#define AOFF(c) ((unsigned)((pr * 128 + ((c) >> 2)) * DD + ((((c) & 3) ^ ((((c) >> 2) >> 1) & 3)) * 16)))
#define BOFF(c) ((unsigned)((b2_0 * IP + ((c) >> 2)) * DD + ((((c) & 3) ^ ((((c) >> 2) >> 1) & 3)) * 16)))
  const unsigned oA0 = AOFF(ca0), oA1 = AOFF(ca1);
  const unsigned oB0 = BOFF(cb0), oB1 = BOFF(cb1), oB2 = BOFF(cb2), oB3 = BOFF(cb3);
  const unsigned BSTR = 8u * IP * DD;     // byte advance per task (+8 b2)

#define ISSUE(AS, BS, k0, bo_) do {                                      \
    async16(A  + oA0 + (k0), (AS) + ca0 * 16);                           \
    async16(A  + oA1 + (k0), (AS) + ca1 * 16);                           \
    async16(Bm + oB0 + (bo_) + (k0), (BS) + cb0 * 16);                   \
    async16(Bm + oB1 + (bo_) + (k0), (BS) + cb1 * 16);                   \
    async16(Bm + oB2 + (bo_) + (k0), (BS) + cb2 * 16);                   \
    if (w == 0) async16(Bm + oB3 + (bo_) + (k0), (BS) + cb3 * 16);       \
  } while (0)

  // acc: 6 main N-tiles (cols (waveN*6+nj)*16, all < 192) + shared tile 12
  i4v am[4][6], a12[2];
#pragma unroll
  for (int mi = 0; mi < 4; ++mi)
#pragma unroll
    for (int nj = 0; nj < 6; ++nj)
      am[mi][nj] = (i4v){0, 0, 0, 0};
  a12[0] = (i4v){0, 0, 0, 0};
  a12[1] = (i4v){0, 0, 0, 0};

  const int swz = q ^ ((m >> 1) & 3);   // logical chunk q -> physical chunk

#define COMPUTE(AS, BS) do {                                               \
    const i4v* Av = (const i4v*)(AS);                                      \
    const i4v* Bv = (const i4v*)(BS);                                      \
    i4v af[4];                                                             \
    _Pragma("unroll")                                                      \
    for (int mi = 0; mi < 4; ++mi)                                         \
      af[mi] = Av[(waveM * 64 + mi * 16 + m) * 4 + swz];                   \
    _Pragma("unroll")                                                      \
    for (int nj = 0; nj < 6; ++nj) {                                       \
      i4v bf = Bv[((waveN * 6 + nj) * 16 + m) * 4 + swz];                  \
      _Pragma("unroll")                                                    \
      for (int mi = 0; mi < 4; ++mi)                                       \
        am[mi][nj] = __builtin_amdgcn_mfma_i32_16x16x64_i8(                \
            af[mi], bf, am[mi][nj], 0, 0, 0);                              \
    }                                                                      \
    {                                                                      \
      i4v bf = Bv[(192 + m) * 4 + swz];                                    \
      if (waveN == 0) {                                                    \
        a12[0] = __builtin_amdgcn_mfma_i32_16x16x64_i8(af[0], bf, a12[0], 0, 0, 0); \
        a12[1] = __builtin_amdgcn_mfma_i32_16x16x64_i8(af[1], bf, a12[1], 0, 0, 0); \
      } else {                                                             \
        a12[0] = __builtin_amdgcn_mfma_i32_16x16x64_i8(af[2], bf, a12[0], 0, 0, 0); \
        a12[1] = __builtin_amdgcn_mfma_i32_16x16x64_i8(af[3], bf, a12[1], 0, 0, 0); \
      }                                                                    \
    }                                                                      \
  } while (0)

  unsigned bo = 0;
  ISSUE(As0, Bs0, 0, 0);
  __syncthreads();                       // cold drain (once per kernel)

#pragma unroll 1
  for (int t = 0; t < NTASK; ++t) {
    for (int ks = 0; ks < 8; ks += 2) {
      ISSUE(As1, Bs1, (ks + 1) * BKK, bo);
      COMPUTE(As0, Bs0);
      __syncthreads();
      if (ks + 2 < 8)            ISSUE(As0, Bs0, (ks + 2) * BKK, bo);
      else if (t + 1 < NTASK)    ISSUE(As0, Bs0, 0, bo + BSTR);  // next task k0
      COMPUTE(As1, Bs1);
      __syncthreads();
    }

    // ---- epilogue: int max over image cols, exact int sum over t ----
    // C/D layout (16x16): col = lane&15, row = (lane>>4)*4 + reg
    const int NEG = -(1 << 30);
#pragma unroll
    for (int mi = 0; mi < 4; ++mi) {
      int v0 = NEG, v1 = NEG, v2 = NEG, v3 = NEG;
#pragma unroll
      for (int nj = 0; nj < 6; ++nj) {        // cols < 192: always valid
        v0 = max(v0, am[mi][nj][0]);
        v1 = max(v1, am[mi][nj][1]);
        v2 = max(v2, am[mi][nj][2]);
        v3 = max(v3, am[mi][nj][3]);
      }
      if ((mi >> 1) == waveN) {               // this wave owns tile 12 for mi
        int z = mi & 1;
        bool valid = m < 4;                   // col 192+m < 196
        v0 = max(v0, valid ? a12[z][0] : NEG);
        v1 = max(v1, valid ? a12[z][1] : NEG);
        v2 = max(v2, valid ? a12[z][2] : NEG);
        v3 = max(v3, valid ? a12[z][3] : NEG);
      }
#pragma unroll
      for (int off = 1; off < 16; off <<= 1) {
        v0 = max(v0, __shfl_xor(v0, off));
        v1 = max(v1, __shfl_xor(v1, off));
        v2 = max(v2, __shfl_xor(v2, off));
        v3 = max(v3, __shfl_xor(v3, off));
      }
      if (m == 0) {
        int rowb = waveM * 64 + mi * 16 + q * 4;
        partial[waveN * 128 + rowb + 0] = v0;
        partial[waveN * 128 + rowb + 1] = v1;
        partial[waveN * 128 + rowb + 2] = v2;
        partial[waveN * 128 + rowb + 3] = v3;
      }
    }
    __syncthreads();

    if (tid < 128) {
      int v = max(partial[tid], partial[128 + tid]);    // max over all 196 i
#pragma unroll
      for (int off = 1; off < 64; off <<= 1) v += __shfl_xor(v, off);  // exact sum over 64 t
      if ((tid & 63) == 0) {
        int b1 = pr * 2 + (tid >> 6);
        sim[b1 * BB + (b2_0 + 8 * t)] = (float)v * (1.0f / 65536.0f);  // /(32*32)/64
      }
    }
    __syncthreads();   // partial[] reuse guard

    // reset accumulators for next task
#pragma unroll
    for (int mi = 0; mi < 4; ++mi)
#pragma unroll
      for (int nj = 0; nj < 6; ++nj)
        am[mi][nj] = (i4v){0, 0, 0, 0};
    a12[0] = (i4v){0, 0, 0, 0};
    a12[1] = (i4v){0, 0, 0, 0};
    bo += BSTR;
  }

  // ---- last-finisher runs the symmetric diagonal cross-entropy ----
  __threadfence();
  if (tid == 0) lastflag = (atomicAdd(counter, 1) == 511);
  __syncthreads();
  if (!lastflag) return;
  __threadfence();

  float* S = (float*)smem;                 // overlay, stride LSTR=132
#pragma unroll
  for (int i = 0; i < 16; ++i) {
    int c = tid + 256 * i;                 // 0..4095 float4 chunks
    int r = c >> 5, col4 = c & 31;
    float4 v = ((const float4*)sim)[c];
    *(float4*)&S[r * LSTR + col4 * 4] = v;
  }
  __syncthreads();

  const int b = tid & 127;
  const bool rowmode = tid < 128;
  const float sc = 1.0f / 0.07f;
  float mx = -3.0e38f;
  for (int jj = 0; jj < BB; ++jj) {
    float v = rowmode ? S[b * LSTR + jj] : S[jj * LSTR + b];
    mx = fmaxf(mx, v);
  }
  float s = 0.f;
  for (int jj = 0; jj < BB; ++jj) {
    float v = rowmode ? S[b * LSTR + jj] : S[jj * LSTR + b];
    s += __expf((v - mx) * sc);
  }
  float d = S[b * LSTR + b];
  float v = (mx - d) * sc + __logf(s);
#pragma unroll
  for (int off = 1; off < 64; off <<= 1) v += __shfl_xor(v, off);
  if ((tid & 63) == 0) red[tid >> 6] = v;
  __syncthreads();
  if (tid == 0) out[0] = (red[0] + red[1] + red[2] + red[3]) * 0.5f / 128.0f;
}

extern "C" void kernel_launch(void* const* d_in, const int* in_sizes, int n_in,
                              void* d_out, int out_size, void* d_ws, size_t ws_size,
                              hipStream_t stream) {
  const float* img = (const float*)d_in[0];  // [128,196,512]
  const float* txt = (const float*)d_in[1];  // [128,64,512]
  float* out = (float*)d_out;

  char* ws = (char*)d_ws;
  const size_t TXT_Q = (size_t)BB * TT * DD;             // 4,194,304 B
  const size_t IMG_Q = (size_t)BB * IP * DD;             // 13,631,488 B
  char* txtq = ws;
  char* imgq = ws + TXT_Q;
  float* sim = (float*)(ws + TXT_Q + IMG_Q);             // 65,536 B
  int* counter = (int*)(ws + TXT_Q + IMG_Q + 65536);     // 4 B

  hipMemsetAsync(counter, 0, 4, stream);
  pack_k<<<TEXT_BLOCKS + IMG_BLOCKS, 256, 0, stream>>>(img, txt, (uint4*)imgq, (uint4*)txtq);
  maxsim_gemm_k<<<512, 256, 0, stream>>>(txtq, imgq, sim, counter, out);
}

// Round 7
// 225.129 us; speedup vs baseline: 1.1874x; 1.1874x over previous
//
#include <hip/hip_runtime.h>
#include <stdint.h>

// ---------------------------------------------------------------------------
// MaxSim InfoNCE on MI355X (gfx950)
//   image_tokens: [128, 196, 512] fp32   (d_in[0])
//   text_tokens : [128,  64, 512] fp32   (d_in[1])
//   out         : scalar fp32 loss
//
// R7 = R5 (proven: INT8 mfma_i32_16x16x64, dbuf prefetch-before-compute
// K-loop, grid 64x128, separate loss kernel) + tile-12 rebalance from R6:
// each wave does 6 private N-tiles (cols 0..191, no mask needed) plus half
// of the shared tile 12 (cols 192..207, mask m<4) -> 26/26 MFMA per wave
// instead of 28/24, and acc drops 112->104 AGPR.
// R6's persistence + fused loss REVERTED: cross-XCD sim race (absmax 0.5)
// and 530 MB of mystery scratch writes. Dumb grid + 2 blocks/CU wins.
// ---------------------------------------------------------------------------

typedef __attribute__((ext_vector_type(4))) int i4v;     // 16 i8 / 4 i32

#define BB 128
#define TT 64
#define II 196
#define IP 208          // padded image tokens per batch (13*16)
#define DD 512
#define BKK 64          // K bytes (=elems) per staging step
#define KSTEPS (DD / BKK)   // 8

static __device__ __forceinline__ void async16(const void* g, void* l) {
  __builtin_amdgcn_global_load_lds(
      (const __attribute__((address_space(1))) void*)g,
      (__attribute__((address_space(3))) void*)l, 16, 0, 0);
}

static __device__ __forceinline__ unsigned q8(float x) {
  float r = rintf(x * 32.0f);                 // RNE, scale 32 (clip 3.97 sigma)
  r = fmaxf(-127.0f, fminf(127.0f, r));
  return (unsigned)((int)r) & 255u;
}
static __device__ __forceinline__ unsigned pk4(float a, float b, float c, float d) {
  return q8(a) | (q8(b) << 8) | (q8(c) << 16) | (q8(d) << 24);
}

// ---- pack: fp32 -> i8 (scale 32). text [128*64,512]; image padded
// ---- [128,208,512], pad rows zeroed. 16 elems / thread.
#define TEXT_BLOCKS 1024     // 1024*256*16 = 128*64*512
#define IMG_BLOCKS  3328     // 3328*256*16 = 128*208*512
__global__ void pack_k(const float* __restrict__ img, const float* __restrict__ txt,
                       uint4* __restrict__ imgq, uint4* __restrict__ txtq) {
  uint4 o;
  if (blockIdx.x < TEXT_BLOCKS) {
    int c = blockIdx.x * 256 + threadIdx.x;         // chunk of 16 elems
    const float4* in4 = (const float4*)txt;
    float4 f0 = in4[4 * c], f1 = in4[4 * c + 1], f2 = in4[4 * c + 2], f3 = in4[4 * c + 3];
    o.x = pk4(f0.x, f0.y, f0.z, f0.w);
    o.y = pk4(f1.x, f1.y, f1.z, f1.w);
    o.z = pk4(f2.x, f2.y, f2.z, f2.w);
    o.w = pk4(f3.x, f3.y, f3.z, f3.w);
    txtq[c] = o;
  } else {
    int c = (blockIdx.x - TEXT_BLOCKS) * 256 + threadIdx.x;
    int e = c * 16;
    int k = e & (DD - 1);
    int tok = e >> 9;
    int b2 = tok / IP;
    int r = tok - b2 * IP;
    if (r < II) {
      const float4* in4 = (const float4*)(img + ((size_t)(b2 * II + r) * DD + k));
      float4 f0 = in4[0], f1 = in4[1], f2 = in4[2], f3 = in4[3];
      o.x = pk4(f0.x, f0.y, f0.z, f0.w);
      o.y = pk4(f1.x, f1.y, f1.z, f1.w);
      o.z = pk4(f2.x, f2.y, f2.z, f2.w);
      o.w = pk4(f3.x, f3.y, f3.z, f3.w);
    } else {
      o = make_uint4(0u, 0u, 0u, 0u);
    }
    imgq[c] = o;
  }
}

// ---- main GEMM + fused max/mean ----
// grid: (64 pairs, 128 b2), block: 256 threads (4 waves, 2x2 over M/N)
__global__ __launch_bounds__(256, 2) void maxsim_gemm_k(
    const char* __restrict__ A,    // text i8 [128*64, 512]
    const char* __restrict__ Bm,   // image i8 [128*208, 512]
    float* __restrict__ sim)       // [128,128] mean-of-max
{
  // Double-buffered tiles, rows of 64 B = 4 chunks of 16 B, XOR swizzle:
  // physical chunk p of row r holds logical chunk p ^ ((r>>1)&3)
  __shared__ __align__(16) char As0[128 * BKK], As1[128 * BKK]; // 8+8 KiB
  __shared__ __align__(16) char Bs0[IP * BKK],  Bs1[IP * BKK];  // 13+13 KiB
  __shared__ int partial[2][128];

  const int pr  = blockIdx.x;       // text pair: b1 in {2pr, 2pr+1}
  const int b2  = blockIdx.y;
  const int tid = threadIdx.x;
  const int w = tid >> 6, l = tid & 63;
  const int m = l & 15, q = l >> 4;
  const int waveM = w >> 1;
  const int waveN = w & 1;

  // chunk -> byte offset (i8: byte == elem)
  const int ca0 = tid, ca1 = tid + 256;
  const int cb0 = tid, cb1 = tid + 256, cb2 = tid + 512, cb3 = 768 + l;
#define AOFF(c) ((unsigned)((pr * 128 + ((c) >> 2)) * DD + ((((c) & 3) ^ ((((c) >> 2) >> 1) & 3)) * 16)))
#define BOFF(c) ((unsigned)((b2 * IP + ((c) >> 2)) * DD + ((((c) & 3) ^ ((((c) >> 2) >> 1) & 3)) * 16)))
  const unsigned oA0 = AOFF(ca0), oA1 = AOFF(ca1);
  const unsigned oB0 = BOFF(cb0), oB1 = BOFF(cb1), oB2 = BOFF(cb2), oB3 = BOFF(cb3);

#define ISSUE(AS, BS, k0) do {                                    \
    async16(A  + oA0 + (k0), (char*)(AS) + ca0 * 16);             \
    async16(A  + oA1 + (k0), (char*)(AS) + ca1 * 16);             \
    async16(Bm + oB0 + (k0), (char*)(BS) + cb0 * 16);             \
    async16(Bm + oB1 + (k0), (char*)(BS) + cb1 * 16);             \
    async16(Bm + oB2 + (k0), (char*)(BS) + cb2 * 16);             \
    if (w == 0) async16(Bm + oB3 + (k0), (char*)(BS) + cb3 * 16); \
  } while (0)

  // acc: 6 private N-tiles (cols (waveN*6+nj)*16, all < 192) + half of
  // shared tile 12 (rows split by waveN within this wave's waveM half)
  i4v am[4][6], a12[2];
#pragma unroll
  for (int mi = 0; mi < 4; ++mi)
#pragma unroll
    for (int nj = 0; nj < 6; ++nj)
      am[mi][nj] = (i4v){0, 0, 0, 0};
  a12[0] = (i4v){0, 0, 0, 0};
  a12[1] = (i4v){0, 0, 0, 0};

  const int swz = q ^ ((m >> 1) & 3);   // logical chunk q -> physical chunk

#define COMPUTE(AS, BS) do {                                               \
    const i4v* Av = (const i4v*)(AS);                                      \
    const i4v* Bv = (const i4v*)(BS);                                      \
    i4v af[4];                                                             \
    _Pragma("unroll")                                                      \
    for (int mi = 0; mi < 4; ++mi)                                         \
      af[mi] = Av[(waveM * 64 + mi * 16 + m) * 4 + swz];                   \
    _Pragma("unroll")                                                      \
    for (int nj = 0; nj < 6; ++nj) {                                       \
      i4v bf = Bv[((waveN * 6 + nj) * 16 + m) * 4 + swz];                  \
      _Pragma("unroll")                                                    \
      for (int mi = 0; mi < 4; ++mi)                                       \
        am[mi][nj] = __builtin_amdgcn_mfma_i32_16x16x64_i8(                \
            af[mi], bf, am[mi][nj], 0, 0, 0);                              \
    }                                                                      \
    {                                                                      \
      i4v bf = Bv[(192 + m) * 4 + swz];                                    \
      if (waveN == 0) {                                                    \
        a12[0] = __builtin_amdgcn_mfma_i32_16x16x64_i8(af[0], bf, a12[0], 0, 0, 0); \
        a12[1] = __builtin_amdgcn_mfma_i32_16x16x64_i8(af[1], bf, a12[1], 0, 0, 0); \
      } else {                                                             \
        a12[0] = __builtin_amdgcn_mfma_i32_16x16x64_i8(af[2], bf, a12[0], 0, 0, 0); \
        a12[1] = __builtin_amdgcn_mfma_i32_16x16x64_i8(af[3], bf, a12[1], 0, 0, 0); \
      }                                                                    \
    }                                                                      \
  } while (0)

  // ---- R2/R5's pipelined K-loop: prefetch-before-compute, sync after ----
  ISSUE(As0, Bs0, 0);
  __syncthreads();                       // cold drain (once)
  for (int ks = 0; ks < KSTEPS; ks += 2) {
    ISSUE(As1, Bs1, (ks + 1) * BKK);
    COMPUTE(As0, Bs0);
    __syncthreads();                     // drains prefetch, hidden by MFMA above
    if (ks + 2 < KSTEPS) ISSUE(As0, Bs0, (ks + 2) * BKK);
    COMPUTE(As1, Bs1);
    __syncthreads();
  }

  // ---- epilogue: int max over image cols, exact int sum over t ----
  // C/D layout (16x16): col = lane&15, row = (lane>>4)*4 + reg
  const int NEG = -(1 << 30);
#pragma unroll
  for (int mi = 0; mi < 4; ++mi) {
    int v0 = NEG, v1 = NEG, v2 = NEG, v3 = NEG;
#pragma unroll
    for (int nj = 0; nj < 6; ++nj) {        // cols < 192: always valid
      v0 = max(v0, am[mi][nj][0]);
      v1 = max(v1, am[mi][nj][1]);
      v2 = max(v2, am[mi][nj][2]);
      v3 = max(v3, am[mi][nj][3]);
    }
    if ((mi >> 1) == waveN) {               // this wave owns tile 12 for mi
      int z = mi & 1;
      bool valid = m < 4;                   // col 192+m < 196
      v0 = max(v0, valid ? a12[z][0] : NEG);
      v1 = max(v1, valid ? a12[z][1] : NEG);
      v2 = max(v2, valid ? a12[z][2] : NEG);
      v3 = max(v3, valid ? a12[z][3] : NEG);
    }
#pragma unroll
    for (int off = 1; off < 16; off <<= 1) {
      v0 = max(v0, __shfl_xor(v0, off));
      v1 = max(v1, __shfl_xor(v1, off));
      v2 = max(v2, __shfl_xor(v2, off));
      v3 = max(v3, __shfl_xor(v3, off));
    }
    if (m == 0) {
      int rowb = waveM * 64 + mi * 16 + q * 4;
      partial[waveN][rowb + 0] = v0;
      partial[waveN][rowb + 1] = v1;
      partial[waveN][rowb + 2] = v2;
      partial[waveN][rowb + 3] = v3;
    }
  }
  __syncthreads();

  if (tid < 128) {
    int v = max(partial[0][tid], partial[1][tid]);      // max over all 196 i
#pragma unroll
    for (int off = 1; off < 64; off <<= 1) v += __shfl_xor(v, off);  // exact sum over 64 t
    if ((tid & 63) == 0) {
      int b1 = pr * 2 + (tid >> 6);
      sim[b1 * BB + b2] = (float)v * (1.0f / 65536.0f); // /(32*32)/64
    }
  }
}

// ---- symmetric diagonal cross-entropy over the 128x128 sim matrix ----
// 256 threads: tid<128 -> row tid (i2t), tid>=128 -> col tid-128 (t2i).
// sim staged in LDS with stride 132 to break row-on-one-bank pattern.
#define LSTR 132
__global__ void loss_k(const float* __restrict__ sim, float* __restrict__ out) {
  __shared__ float S[BB * LSTR];           // 67,584 B
  __shared__ float red[4];
  const int tid = threadIdx.x;             // 0..255
#pragma unroll
  for (int i = 0; i < 16; ++i) {
    int c = tid + 256 * i;                 // 0..4095 float4 chunks
    int r = c >> 5, col4 = c & 31;
    float4 v = ((const float4*)sim)[c];
    *(float4*)&S[r * LSTR + col4 * 4] = v;
  }
  __syncthreads();

  const int b = tid & 127;
  const bool rowmode = tid < 128;
  const float sc = 1.0f / 0.07f;
  float mx = -3.0e38f;
  for (int j = 0; j < BB; ++j) {
    float v = rowmode ? S[b * LSTR + j] : S[j * LSTR + b];
    mx = fmaxf(mx, v);
  }
  float s = 0.f;
  for (int j = 0; j < BB; ++j) {
    float v = rowmode ? S[b * LSTR + j] : S[j * LSTR + b];
    s += __expf((v - mx) * sc);
  }
  float d = S[b * LSTR + b];
  float v = (mx - d) * sc + __logf(s);     // lse - diag for this row/col
#pragma unroll
  for (int off = 1; off < 64; off <<= 1) v += __shfl_xor(v, off);
  if ((tid & 63) == 0) red[tid >> 6] = v;
  __syncthreads();
  if (tid == 0) out[0] = (red[0] + red[1] + red[2] + red[3]) * 0.5f / 128.0f;
}

extern "C" void kernel_launch(void* const* d_in, const int* in_sizes, int n_in,
                              void* d_out, int out_size, void* d_ws, size_t ws_size,
                              hipStream_t stream) {
  const float* img = (const float*)d_in[0];  // [128,196,512]
  const float* txt = (const float*)d_in[1];  // [128,64,512]
  float* out = (float*)d_out;

  char* ws = (char*)d_ws;
  const size_t TXT_Q = (size_t)BB * TT * DD;             // 4,194,304 B
  const size_t IMG_Q = (size_t)BB * IP * DD;             // 13,631,488 B
  char* txtq = ws;
  char* imgq = ws + TXT_Q;
  float* sim = (float*)(ws + TXT_Q + IMG_Q);             // 65,536 B

  pack_k<<<TEXT_BLOCKS + IMG_BLOCKS, 256, 0, stream>>>(img, txt, (uint4*)imgq, (uint4*)txtq);
  maxsim_gemm_k<<<dim3(64, 128), 256, 0, stream>>>(txtq, imgq, sim);
  loss_k<<<1, 256, 0, stream>>>(sim, out);
}